// Round 1
// baseline (16123.021 us; speedup 1.0000x reference)
//
#include <hip/hip_runtime.h>

// Problem dims (fixed by the reference)
#define Bsz 256
#define Tsz 512
#define Isz 128
#define Hsz 512
#define G3  1536   // 3*H

typedef __attribute__((ext_vector_type(8))) short short8;
typedef __attribute__((ext_vector_type(4))) float f32x4;

__device__ __forceinline__ unsigned short f2bf(float x) {
  unsigned int u = __builtin_bit_cast(unsigned int, x);
  u += 0x7fffu + ((u >> 16) & 1u);      // RNE round to bf16
  return (unsigned short)(u >> 16);
}

__device__ __forceinline__ float sig_(float x) { return 1.0f / (1.0f + expf(-x)); }

// fp32 -> bf16 (as ushort) cast, 4 elems/thread
__global__ void cast_bf16_k(const float* __restrict__ src,
                            unsigned short* __restrict__ dst, int n4) {
  int i = blockIdx.x * blockDim.x + threadIdx.x;
  if (i >= n4) return;
  const float4 v = reinterpret_cast<const float4*>(src)[i];
  ushort4 o;
  o.x = f2bf(v.x); o.y = f2bf(v.y); o.z = f2bf(v.z); o.w = f2bf(v.w);
  reinterpret_cast<ushort4*>(dst)[i] = o;
}

// One GRU time step (generic over layer).
//   gi = x_t @ Wih^T  (Kx = 128 or 512),  gh = h_prev @ Whh^T (K = 512)
//   r = sig(gi_r + bi_r + gh_r + bh_r); z likewise;
//   n = tanh(gi_n + bi_n + r*(gh_n + bh_n)); h = (1-z)*n + z*h_prev
// Grid: (32 j-tiles of 16 h-cols, 4 b-tiles of 64 rows), block 256 (4 waves).
// Wave w handles rows [btile*64 + 16w, +16). MFMA 16x16x32 bf16, fp32 acc.
__global__ __launch_bounds__(256) void gru_step(
    const unsigned short* __restrict__ xb, int xStride, int Kx,
    const unsigned short* __restrict__ Wih,   // [1536, Kx] row-major bf16
    const unsigned short* __restrict__ Whh,   // [1536, 512] row-major bf16
    const float* __restrict__ bi, const float* __restrict__ bh,
    const float* __restrict__ hprev, const unsigned short* __restrict__ hprevb,
    float* __restrict__ hnext, unsigned short* __restrict__ hnextb)
{
  const int tid = threadIdx.x;
  const int w   = tid >> 6;
  const int l   = tid & 63;
  const int lm  = l & 15;
  const int lk  = (l >> 4) << 3;           // k-chunk offset (0,8,16,24)
  const int rowbase = blockIdx.y * 64 + w * 16;
  const int jt  = blockIdx.x * 16;         // h-column tile base

  const f32x4 zero = {0.f, 0.f, 0.f, 0.f};
  f32x4 acc_i0 = zero, acc_i1 = zero, acc_i2 = zero;
  f32x4 acc_h0 = zero, acc_h1 = zero, acc_h2 = zero;

  const int aRow = rowbase + lm;

  // ---- input-projection part: A = x_t rows, B^T = Wih rows (K-contiguous)
  {
    const unsigned short* xrow = xb + (size_t)aRow * xStride + lk;
    const unsigned short* w0 = Wih + (size_t)(       jt + lm) * Kx + lk;
    const unsigned short* w1 = Wih + (size_t)( 512 + jt + lm) * Kx + lk;
    const unsigned short* w2 = Wih + (size_t)(1024 + jt + lm) * Kx + lk;
    #pragma unroll 4
    for (int k0 = 0; k0 < Kx; k0 += 32) {
      short8 a  = *reinterpret_cast<const short8*>(xrow + k0);
      short8 b0 = *reinterpret_cast<const short8*>(w0 + k0);
      short8 b1 = *reinterpret_cast<const short8*>(w1 + k0);
      short8 b2 = *reinterpret_cast<const short8*>(w2 + k0);
      acc_i0 = __builtin_amdgcn_mfma_f32_16x16x32_bf16(a, b0, acc_i0, 0, 0, 0);
      acc_i1 = __builtin_amdgcn_mfma_f32_16x16x32_bf16(a, b1, acc_i1, 0, 0, 0);
      acc_i2 = __builtin_amdgcn_mfma_f32_16x16x32_bf16(a, b2, acc_i2, 0, 0, 0);
    }
  }
  // ---- hidden-projection part: A = h_prev rows (bf16 shadow), B^T = Whh
  {
    const unsigned short* hrow = hprevb + (size_t)aRow * Hsz + lk;
    const unsigned short* v0 = Whh + (size_t)(       jt + lm) * Hsz + lk;
    const unsigned short* v1 = Whh + (size_t)( 512 + jt + lm) * Hsz + lk;
    const unsigned short* v2 = Whh + (size_t)(1024 + jt + lm) * Hsz + lk;
    #pragma unroll 4
    for (int k0 = 0; k0 < Hsz; k0 += 32) {
      short8 a  = *reinterpret_cast<const short8*>(hrow + k0);
      short8 b0 = *reinterpret_cast<const short8*>(v0 + k0);
      short8 b1 = *reinterpret_cast<const short8*>(v1 + k0);
      short8 b2 = *reinterpret_cast<const short8*>(v2 + k0);
      acc_h0 = __builtin_amdgcn_mfma_f32_16x16x32_bf16(a, b0, acc_h0, 0, 0, 0);
      acc_h1 = __builtin_amdgcn_mfma_f32_16x16x32_bf16(a, b1, acc_h1, 0, 0, 0);
      acc_h2 = __builtin_amdgcn_mfma_f32_16x16x32_bf16(a, b2, acc_h2, 0, 0, 0);
    }
  }

  // ---- gates + state update. C/D map: col = l&15, row = (l>>4)*4 + q (m89)
  const int col = jt + lm;
  const float bir = bi[col], biz = bi[512 + col], bin = bi[1024 + col];
  const float bhr = bh[col], bhz = bh[512 + col], bhn = bh[1024 + col];
  const int r0 = rowbase + ((l >> 4) << 2);
  #pragma unroll
  for (int q = 0; q < 4; ++q) {
    const int row = r0 + q;
    const float r = sig_(acc_i0[q] + bir + acc_h0[q] + bhr);
    const float z = sig_(acc_i1[q] + biz + acc_h1[q] + bhz);
    const float n = tanhf(acc_i2[q] + bin + r * (acc_h2[q] + bhn));
    const float ho = hprev[(size_t)row * Hsz + col];
    const float hv = (1.0f - z) * n + z * ho;
    hnext[(size_t)row * Hsz + col] = hv;
    hnextb[(size_t)row * Hsz + col] = f2bf(hv);
  }
}

// Final FC + sigmoid: out[b] = sig(h[b,:] . fc_w + fc_b)
__global__ void fc_k(const float* __restrict__ h, const float* __restrict__ fw,
                     const float* __restrict__ fb, float* __restrict__ out) {
  const int b = threadIdx.x;   // 256 threads, 1 block
  float s = fb[0];
  const float* hr = h + (size_t)b * Hsz;
  #pragma unroll 8
  for (int k = 0; k < Hsz; ++k) s += hr[k] * fw[k];
  out[b] = 1.0f / (1.0f + expf(-s));
}

extern "C" void kernel_launch(void* const* d_in, const int* in_sizes, int n_in,
                              void* d_out, int out_size, void* d_ws, size_t ws_size,
                              hipStream_t stream) {
  (void)in_sizes; (void)n_in; (void)out_size; (void)ws_size;
  const float* X    = (const float*)d_in[0];
  const float* Wih0 = (const float*)d_in[1];
  const float* Whh0 = (const float*)d_in[2];
  const float* bi0  = (const float*)d_in[3];
  const float* bh0  = (const float*)d_in[4];
  const float* Wih1 = (const float*)d_in[5];
  const float* Whh1 = (const float*)d_in[6];
  const float* bi1  = (const float*)d_in[7];
  const float* bh1  = (const float*)d_in[8];
  const float* fcw  = (const float*)d_in[9];
  const float* fcb  = (const float*)d_in[10];
  float* out = (float*)d_out;
  char*  ws  = (char*)d_ws;

  // ---- workspace layout (256B aligned), total ~41 MB
  size_t off = 0;
  auto alloc = [&](size_t bytes) { size_t r = off; off += (bytes + 255) & ~(size_t)255; return r; };
  unsigned short* Wih0b = (unsigned short*)(ws + alloc((size_t)G3 * Isz * 2));
  unsigned short* Whh0b = (unsigned short*)(ws + alloc((size_t)G3 * Hsz * 2));
  unsigned short* Wih1b = (unsigned short*)(ws + alloc((size_t)G3 * Hsz * 2));
  unsigned short* Whh1b = (unsigned short*)(ws + alloc((size_t)G3 * Hsz * 2));
  unsigned short* Xb    = (unsigned short*)(ws + alloc((size_t)Bsz * Tsz * Isz * 2));
  const size_t hoff = off;
  float* h0[2];          h0[0]  = (float*)(ws + alloc((size_t)Bsz * Hsz * 4));
                         h0[1]  = (float*)(ws + alloc((size_t)Bsz * Hsz * 4));
  float* h1[2];          h1[0]  = (float*)(ws + alloc((size_t)Bsz * Hsz * 4));
                         h1[1]  = (float*)(ws + alloc((size_t)Bsz * Hsz * 4));
  unsigned short* h0b[2]; h0b[0] = (unsigned short*)(ws + alloc((size_t)Bsz * Hsz * 2));
                          h0b[1] = (unsigned short*)(ws + alloc((size_t)Bsz * Hsz * 2));
  unsigned short* h1b[2]; h1b[0] = (unsigned short*)(ws + alloc((size_t)Bsz * Hsz * 2));
                          h1b[1] = (unsigned short*)(ws + alloc((size_t)Bsz * Hsz * 2));
  const size_t hbytes = off - hoff;

  // ---- prep: cast weights + X to bf16, zero h state
  auto cast = [&](const float* s, unsigned short* d, int n) {
    int n4 = n / 4;
    cast_bf16_k<<<(n4 + 255) / 256, 256, 0, stream>>>(s, d, n4);
  };
  cast(Wih0, Wih0b, G3 * Isz);
  cast(Whh0, Whh0b, G3 * Hsz);
  cast(Wih1, Wih1b, G3 * Hsz);
  cast(Whh1, Whh1b, G3 * Hsz);
  cast(X,    Xb,    Bsz * Tsz * Isz);
  hipMemsetAsync(ws + hoff, 0, hbytes, stream);

  // ---- recurrence: 512 steps x 2 layers, ping-pong h buffers
  const dim3 grid(Hsz / 16, Bsz / 64);
  int p = 0;
  for (int t = 0; t < Tsz; ++t) {
    gru_step<<<grid, 256, 0, stream>>>(Xb + (size_t)t * Isz, Tsz * Isz, Isz,
                                       Wih0b, Whh0b, bi0, bh0,
                                       h0[p], h0b[p], h0[p ^ 1], h0b[p ^ 1]);
    gru_step<<<grid, 256, 0, stream>>>(h0b[p ^ 1], Hsz, Hsz,
                                       Wih1b, Whh1b, bi1, bh1,
                                       h1[p], h1b[p], h1[p ^ 1], h1b[p ^ 1]);
    p ^= 1;
  }
  // after 512 steps (even), final h1 lives in h1[0]
  fc_k<<<1, 256, 0, stream>>>(h1[0], fcw, fcb, out);
}

// Round 2
// 12492.388 us; speedup vs baseline: 1.2906x; 1.2906x over previous
//
#include <hip/hip_runtime.h>

#define Bsz 256
#define Tsz 512
#define Isz 128
#define Hsz 512
#define NWG 256

typedef __attribute__((ext_vector_type(8))) short short8;
typedef __attribute__((ext_vector_type(4))) float f32x4;

__device__ __forceinline__ unsigned short f2bf(float x) {
  unsigned int u = __builtin_bit_cast(unsigned int, x);
  u += 0x7fffu + ((u >> 16) & 1u);      // RNE round to bf16
  return (unsigned short)(u >> 16);
}
__device__ __forceinline__ float sig_(float x) { return 1.0f / (1.0f + expf(-x)); }

// ---------------- prep kernels ----------------
__global__ void cast_bf16_k(const float* __restrict__ src,
                            unsigned short* __restrict__ dst, int n4) {
  int i = blockIdx.x * blockDim.x + threadIdx.x;
  if (i >= n4) return;
  const float4 v = reinterpret_cast<const float4*>(src)[i];
  ushort4 o;
  o.x = f2bf(v.x); o.y = f2bf(v.y); o.z = f2bf(v.z); o.w = f2bf(v.w);
  reinterpret_cast<ushort4*>(dst)[i] = o;
}

// X [B][T][128] fp32 -> Xt [T][B][128] bf16
__global__ void castX_k(const float* __restrict__ X, unsigned short* __restrict__ Xt) {
  int i = blockIdx.x * blockDim.x + threadIdx.x;   // B*T*128/4 threads
  const int e = i * 4;
  const int k = e & 127;
  const int t = (e >> 7) & 511;
  const int b = e >> 16;
  float4 v = *reinterpret_cast<const float4*>(X + e);
  ushort4 o;
  o.x = f2bf(v.x); o.y = f2bf(v.y); o.z = f2bf(v.z); o.w = f2bf(v.w);
  *reinterpret_cast<ushort4*>(Xt + ((size_t)t * Bsz + b) * Isz + k) = o;
}

__global__ void fc_k(const float* __restrict__ h, const float* __restrict__ fw,
                     const float* __restrict__ fb, float* __restrict__ out) {
  const int b = threadIdx.x;   // 256 threads, 1 block
  float s = fb[0];
  const float* hr = h + (size_t)b * Hsz;
  #pragma unroll 8
  for (int k = 0; k < Hsz; ++k) s += hr[k] * fw[k];
  out[b] = 1.0f / (1.0f + expf(-s));
}

// ---------------- persistent GRU kernel ----------------
// Copy this WG's weight slice (cols jt*16..+16 of each gate) into LDS,
// layout per gate-panel: [K/8][16 cols][8 k] bf16 -> conflict-free ds_read_b128.
__device__ __forceinline__ void load_slice(const unsigned short* __restrict__ W, int K,
                                           int kcShift, int jt,
                                           unsigned short* lds, int base) {
  const int total = (3 * 16) << kcShift;           // 3 gates * 16 cols * K/8 chunks
  for (int idx = threadIdx.x; idx < total; idx += 256) {
    const int j  = idx & 15;
    const int t2 = idx >> 4;
    const int c  = t2 & ((1 << kcShift) - 1);
    const int g  = t2 >> kcShift;
    const unsigned short* src = W + (size_t)(g * 512 + jt * 16 + j) * K + c * 8;
    short8 v = *reinterpret_cast<const short8*>(src);
    *reinterpret_cast<short8*>(lds + base + ((g << kcShift) + c) * 128 + j * 8) = v;
  }
}

// Accumulate 3 gate panels over KITER k-steps of 32.
template<int KITER, int PSTRIDE>
__device__ __forceinline__ void gemm3(const unsigned short* __restrict__ Aptr,
                                      const unsigned short* lds, int ldsoff,
                                      f32x4& ar, f32x4& az, f32x4& an) {
  #pragma unroll
  for (int i = 0; i < KITER; ++i) {
    short8 a  = *reinterpret_cast<const short8*>(Aptr + i * 32);
    short8 b0 = *reinterpret_cast<const short8*>(lds + ldsoff + i * 512);
    short8 b1 = *reinterpret_cast<const short8*>(lds + ldsoff + PSTRIDE + i * 512);
    short8 b2 = *reinterpret_cast<const short8*>(lds + ldsoff + 2 * PSTRIDE + i * 512);
    ar = __builtin_amdgcn_mfma_f32_16x16x32_bf16(a, b0, ar, 0, 0, 0);
    az = __builtin_amdgcn_mfma_f32_16x16x32_bf16(a, b1, az, 0, 0, 0);
    an = __builtin_amdgcn_mfma_f32_16x16x32_bf16(a, b2, an, 0, 0, 0);
  }
}

// Sense-reversal grid barrier, agent scope. cnt and gen 128B apart.
__device__ __forceinline__ void gbar(unsigned* cnt, unsigned* gen) {
  __syncthreads();
  if (threadIdx.x == 0) {
    unsigned g = __hip_atomic_load(gen, __ATOMIC_RELAXED, __HIP_MEMORY_SCOPE_AGENT);
    unsigned old = __hip_atomic_fetch_add(cnt, 1u, __ATOMIC_ACQ_REL, __HIP_MEMORY_SCOPE_AGENT);
    if (old == NWG - 1) {
      __hip_atomic_store(cnt, 0u, __ATOMIC_RELAXED, __HIP_MEMORY_SCOPE_AGENT);
      __hip_atomic_store(gen, g + 1u, __ATOMIC_RELEASE, __HIP_MEMORY_SCOPE_AGENT);
    } else {
      unsigned iter = 0;
      while (__hip_atomic_load(gen, __ATOMIC_RELAXED, __HIP_MEMORY_SCOPE_AGENT) == g) {
        __builtin_amdgcn_s_sleep(2);
        if (++iter > (1u << 27)) break;    // fail loud, not hung
      }
    }
  }
  __syncthreads();
  (void)__hip_atomic_load(gen, __ATOMIC_ACQUIRE, __HIP_MEMORY_SCOPE_AGENT);
}

// LDS map (ushort units): Wih0 @0 (panel 2048), Whh0 @6144 (panel 8192),
// Wih1 @30720, Whh1 @55296. Total 79872 ushorts = 159744 B.
__global__ __launch_bounds__(256, 1) void gru_persist(
    const unsigned short* __restrict__ Xt,
    const unsigned short* __restrict__ Wih0b, const unsigned short* __restrict__ Whh0b,
    const unsigned short* __restrict__ Wih1b, const unsigned short* __restrict__ Whh1b,
    const float* __restrict__ bi0, const float* __restrict__ bh0,
    const float* __restrict__ bi1, const float* __restrict__ bh1,
    float* __restrict__ h0f, float* __restrict__ h1f,
    unsigned short* __restrict__ h0s0, unsigned short* __restrict__ h0s1,
    unsigned short* __restrict__ h1s0, unsigned short* __restrict__ h1s1,
    unsigned* __restrict__ bar)
{
  extern __shared__ unsigned short lds[];
  const int tid = threadIdx.x;
  const int wg  = blockIdx.x;
  const int jt  = wg & 31;          // jt-major across XCDs: small per-XCD weight footprint
  const int bt  = wg >> 5;
  const int w   = tid >> 6;
  const int l   = tid & 63;
  const int lm  = l & 15;
  const int lq  = l >> 4;
  const int layer = w >> 1;         // waves 0,1 -> layer0; 2,3 -> layer1
  const int r16   = w & 1;          // 16-row half within the WG's 32 rows

  load_slice(Wih0b, Isz, 4, jt, lds, 0);
  load_slice(Whh0b, Hsz, 6, jt, lds, 6144);
  load_slice(Wih1b, Hsz, 6, jt, lds, 30720);
  load_slice(Whh1b, Hsz, 6, jt, lds, 55296);
  __syncthreads();

  const int col  = jt * 16 + lm;
  const int aRow = bt * 32 + r16 * 16 + lm;
  const int rowb = bt * 32 + r16 * 16 + lq * 4;
  const int ldsoff = lq * 128 + lm * 8;

  const float* bi = layer ? bi1 : bi0;
  const float* bh = layer ? bh1 : bh0;
  const float brb  = bi[col] + bh[col];
  const float bzb  = bi[512 + col] + bh[512 + col];
  const float binb = bi[1024 + col];
  const float bhnb = bh[1024 + col];
  float* hf = layer ? h1f : h0f;

  unsigned short* h0s[2] = {h0s0, h0s1};
  unsigned short* h1s[2] = {h1s0, h1s1};
  const f32x4 zero = {0.f, 0.f, 0.f, 0.f};

  // phase p: layer0 computes h0[p] (p<T); layer1 computes h1[p-1] (p>=1)
  for (int p = 0; p <= Tsz; ++p) {
    const bool active = layer ? (p >= 1) : (p < Tsz);
    if (active) {
      f32x4 ar = zero, az = zero, ain = zero, ahn = zero;
      if (!layer) {
        const unsigned short* Ax = Xt + ((size_t)p * Bsz + aRow) * Isz + lq * 8;
        const unsigned short* Ah = h0s[(p + 1) & 1] + (size_t)aRow * Hsz + lq * 8;
        gemm3<4, 2048>(Ax, lds, ldsoff + 0,    ar, az, ain);
        gemm3<16, 8192>(Ah, lds, ldsoff + 6144, ar, az, ahn);
      } else {
        const unsigned short* Ai = h0s[(p + 1) & 1] + (size_t)aRow * Hsz + lq * 8;
        const unsigned short* Ah = h1s[p & 1]       + (size_t)aRow * Hsz + lq * 8;
        gemm3<16, 8192>(Ai, lds, ldsoff + 30720, ar, az, ain);
        gemm3<16, 8192>(Ah, lds, ldsoff + 55296, ar, az, ahn);
      }
      unsigned short* hw = layer ? h1s[(p + 1) & 1] : h0s[p & 1];
      #pragma unroll
      for (int q = 0; q < 4; ++q) {
        const int row = rowb + q;                        // C/D map (m89)
        const float r = sig_(ar[q] + brb);
        const float z = sig_(az[q] + bzb);
        const float n = tanhf(ain[q] + binb + r * (ahn[q] + bhnb));
        const size_t idx = (size_t)row * Hsz + col;
        const float hp = hf[idx];                        // own thread's prior write
        const float hv = (1.f - z) * n + z * hp;
        hf[idx] = hv;
        hw[idx] = f2bf(hv);
      }
    }
    gbar(bar, bar + 32);
  }
}

// ---------------- host ----------------
extern "C" void kernel_launch(void* const* d_in, const int* in_sizes, int n_in,
                              void* d_out, int out_size, void* d_ws, size_t ws_size,
                              hipStream_t stream) {
  (void)in_sizes; (void)n_in; (void)out_size; (void)ws_size;
  const float* X    = (const float*)d_in[0];
  const float* Wih0 = (const float*)d_in[1];
  const float* Whh0 = (const float*)d_in[2];
  const float* bi0  = (const float*)d_in[3];
  const float* bh0  = (const float*)d_in[4];
  const float* Wih1 = (const float*)d_in[5];
  const float* Whh1 = (const float*)d_in[6];
  const float* bi1  = (const float*)d_in[7];
  const float* bh1  = (const float*)d_in[8];
  const float* fcw  = (const float*)d_in[9];
  const float* fcb  = (const float*)d_in[10];
  float* out = (float*)d_out;
  char*  ws  = (char*)d_ws;

  size_t off = 0;
  auto alloc = [&](size_t bytes) { size_t r = off; off += (bytes + 255) & ~(size_t)255; return r; };
  unsigned short* Wih0b = (unsigned short*)(ws + alloc((size_t)3 * Hsz * Isz * 2));
  unsigned short* Whh0b = (unsigned short*)(ws + alloc((size_t)3 * Hsz * Hsz * 2));
  unsigned short* Wih1b = (unsigned short*)(ws + alloc((size_t)3 * Hsz * Hsz * 2));
  unsigned short* Whh1b = (unsigned short*)(ws + alloc((size_t)3 * Hsz * Hsz * 2));
  unsigned short* Xt    = (unsigned short*)(ws + alloc((size_t)Bsz * Tsz * Isz * 2));
  const size_t zoff = off;
  float* h0f = (float*)(ws + alloc((size_t)Bsz * Hsz * 4));
  float* h1f = (float*)(ws + alloc((size_t)Bsz * Hsz * 4));
  unsigned short* h0s0 = (unsigned short*)(ws + alloc((size_t)Bsz * Hsz * 2));
  unsigned short* h0s1 = (unsigned short*)(ws + alloc((size_t)Bsz * Hsz * 2));
  unsigned short* h1s0 = (unsigned short*)(ws + alloc((size_t)Bsz * Hsz * 2));
  unsigned short* h1s1 = (unsigned short*)(ws + alloc((size_t)Bsz * Hsz * 2));
  unsigned* bar = (unsigned*)(ws + alloc(256));
  const size_t zbytes = off - zoff;

  auto cast = [&](const float* s, unsigned short* d, int n) {
    int n4 = n / 4;
    cast_bf16_k<<<(n4 + 255) / 256, 256, 0, stream>>>(s, d, n4);
  };
  cast(Wih0, Wih0b, 3 * Hsz * Isz);
  cast(Whh0, Whh0b, 3 * Hsz * Hsz);
  cast(Wih1, Wih1b, 3 * Hsz * Hsz);
  cast(Whh1, Whh1b, 3 * Hsz * Hsz);
  castX_k<<<(Bsz * Tsz * Isz / 4 + 255) / 256, 256, 0, stream>>>(X, Xt);
  hipMemsetAsync(ws + zoff, 0, zbytes, stream);   // h states + barrier = 0

  (void)hipFuncSetAttribute((const void*)gru_persist,
                            hipFuncAttributeMaxDynamicSharedMemorySize, 159744);
  gru_persist<<<NWG, 256, 159744, stream>>>(Xt, Wih0b, Whh0b, Wih1b, Whh1b,
                                            bi0, bh0, bi1, bh1,
                                            h0f, h1f, h0s0, h0s1, h1s0, h1s1, bar);
  fc_k<<<1, 256, 0, stream>>>(h1f, fcw, fcb, out);
}

// Round 3
// 5782.211 us; speedup vs baseline: 2.7884x; 2.1605x over previous
//
#include <hip/hip_runtime.h>

#define Bsz 256
#define Tsz 512
#define Isz 128
#define Hsz 512
#define NWG 256
#define SCOPE_AGENT __HIP_MEMORY_SCOPE_AGENT

typedef __attribute__((ext_vector_type(8))) short short8;
typedef __attribute__((ext_vector_type(4))) float f32x4;

__device__ __forceinline__ unsigned short f2bf(float x) {
  unsigned int u = __builtin_bit_cast(unsigned int, x);
  u += 0x7fffu + ((u >> 16) & 1u);      // RNE round to bf16
  return (unsigned short)(u >> 16);
}
__device__ __forceinline__ float sig_(float x) { return 1.0f / (1.0f + expf(-x)); }

// device-coherent (agent-scope) 16B load as 2x8B relaxed atomics
__device__ __forceinline__ short8 ldc16(const unsigned short* p) {
  const unsigned long long* q = (const unsigned long long*)p;
  union { short8 s; unsigned long long u[2]; } r;
  r.u[0] = __hip_atomic_load(q,     __ATOMIC_RELAXED, SCOPE_AGENT);
  r.u[1] = __hip_atomic_load(q + 1, __ATOMIC_RELAXED, SCOPE_AGENT);
  return r.s;
}
__device__ __forceinline__ void stc2(unsigned short* p, unsigned short v) {
  __hip_atomic_store(p, v, __ATOMIC_RELAXED, SCOPE_AGENT);
}

// ---------------- prep kernels ----------------
__global__ void cast_bf16_k(const float* __restrict__ src,
                            unsigned short* __restrict__ dst, int n4) {
  int i = blockIdx.x * blockDim.x + threadIdx.x;
  if (i >= n4) return;
  const float4 v = reinterpret_cast<const float4*>(src)[i];
  ushort4 o;
  o.x = f2bf(v.x); o.y = f2bf(v.y); o.z = f2bf(v.z); o.w = f2bf(v.w);
  reinterpret_cast<ushort4*>(dst)[i] = o;
}

// X [B][T][128] fp32 -> Xt [T][B][128] bf16
__global__ void castX_k(const float* __restrict__ X, unsigned short* __restrict__ Xt) {
  int i = blockIdx.x * blockDim.x + threadIdx.x;   // B*T*128/4 threads
  const int e = i * 4;
  const int k = e & 127;
  const int t = (e >> 7) & 511;
  const int b = e >> 16;
  float4 v = *reinterpret_cast<const float4*>(X + e);
  ushort4 o;
  o.x = f2bf(v.x); o.y = f2bf(v.y); o.z = f2bf(v.z); o.w = f2bf(v.w);
  *reinterpret_cast<ushort4*>(Xt + ((size_t)t * Bsz + b) * Isz + k) = o;
}

__global__ void fc_k(const float* __restrict__ h, const float* __restrict__ fw,
                     const float* __restrict__ fb, float* __restrict__ out) {
  const int b = threadIdx.x;   // 256 threads, 1 block
  float s = fb[0];
  const float* hr = h + (size_t)b * Hsz;
  #pragma unroll 8
  for (int k = 0; k < Hsz; ++k) s += hr[k] * fw[k];
  out[b] = 1.0f / (1.0f + expf(-s));
}

// ---------------- persistent GRU kernel ----------------
// Weight slice (cols jt*16..+16 of each gate) -> LDS.
// Per gate-panel layout: [K/8][16 cols][8 k] bf16 -> conflict-free ds_read_b128.
__device__ __forceinline__ void load_slice(const unsigned short* __restrict__ W, int K,
                                           int kcShift, int jt,
                                           unsigned short* lds, int base) {
  const int total = (3 * 16) << kcShift;           // 3 gates * 16 cols * K/8 chunks
  for (int idx = threadIdx.x; idx < total; idx += 256) {
    const int j  = idx & 15;
    const int t2 = idx >> 4;
    const int c  = t2 & ((1 << kcShift) - 1);
    const int g  = t2 >> kcShift;
    const unsigned short* src = W + (size_t)(g * 512 + jt * 16 + j) * K + c * 8;
    short8 v = *reinterpret_cast<const short8*>(src);
    *reinterpret_cast<short8*>(lds + base + ((g << kcShift) + c) * 128 + j * 8) = v;
  }
}

// 3 gate panels over KITER k-steps of 32. COH: device-coherent A loads.
template<int KITER, int PSTRIDE, bool COH>
__device__ __forceinline__ void gemm3(const unsigned short* __restrict__ Aptr,
                                      const unsigned short* lds, int ldsoff,
                                      f32x4& ar, f32x4& az, f32x4& an) {
  #pragma unroll
  for (int i = 0; i < KITER; ++i) {
    short8 a = COH ? ldc16(Aptr + i * 32)
                   : *reinterpret_cast<const short8*>(Aptr + i * 32);
    short8 b0 = *reinterpret_cast<const short8*>(lds + ldsoff + i * 512);
    short8 b1 = *reinterpret_cast<const short8*>(lds + ldsoff + PSTRIDE + i * 512);
    short8 b2 = *reinterpret_cast<const short8*>(lds + ldsoff + 2 * PSTRIDE + i * 512);
    ar = __builtin_amdgcn_mfma_f32_16x16x32_bf16(a, b0, ar, 0, 0, 0);
    az = __builtin_amdgcn_mfma_f32_16x16x32_bf16(a, b1, az, 0, 0, 0);
    an = __builtin_amdgcn_mfma_f32_16x16x32_bf16(a, b2, an, 0, 0, 0);
  }
}

// Per-group (32 WGs, same bt) flag barrier. flags[wg*32] holds last phase done.
__device__ __forceinline__ void groupbar(unsigned* flags, int wg, int bt, unsigned ph) {
  asm volatile("s_waitcnt vmcnt(0)" ::: "memory");   // every wave: own stores visible
  __syncthreads();
  const int tid = threadIdx.x;
  if (tid == 0)
    __hip_atomic_store(&flags[wg * 32], ph, __ATOMIC_RELAXED, SCOPE_AGENT);
  if (tid < 32) {
    const unsigned* f = &flags[(bt + 8 * tid) * 32];
    int it = 0;
    while (__hip_atomic_load(f, __ATOMIC_RELAXED, SCOPE_AGENT) < ph) {
      __builtin_amdgcn_s_sleep(1);
      if (++it > (1 << 20)) break;                   // fail loud, not hung
    }
  }
  __syncthreads();
  asm volatile("" ::: "memory");
}

// LDS map (ushort units): Wih0 @0 (panel 2048), Whh0 @6144 (panel 8192),
// Wih1 @30720, Whh1 @55296. Total 79872 ushorts = 159744 B.
__global__ __launch_bounds__(256, 1) void gru_persist(
    const unsigned short* __restrict__ Xt,
    const unsigned short* __restrict__ Wih0b, const unsigned short* __restrict__ Whh0b,
    const unsigned short* __restrict__ Wih1b, const unsigned short* __restrict__ Whh1b,
    const float* __restrict__ bi0, const float* __restrict__ bh0,
    const float* __restrict__ bi1, const float* __restrict__ bh1,
    float* __restrict__ h1f,
    unsigned short* __restrict__ h0s0, unsigned short* __restrict__ h0s1,
    unsigned short* __restrict__ h1s0, unsigned short* __restrict__ h1s1,
    unsigned* __restrict__ flags)
{
  extern __shared__ unsigned short lds[];
  const int tid = threadIdx.x;
  const int wg  = blockIdx.x;
  const int bt  = wg & 7;           // one bt-group per XCD (round-robin dispatch)
  const int jt  = wg >> 3;          // 32 column tiles
  const int w   = tid >> 6;
  const int l   = tid & 63;
  const int lm  = l & 15;
  const int lq  = l >> 4;
  const int layer = w >> 1;         // waves 0,1 -> layer0; 2,3 -> layer1
  const int r16   = w & 1;

  load_slice(Wih0b, Isz, 4, jt, lds, 0);
  load_slice(Whh0b, Hsz, 6, jt, lds, 6144);
  load_slice(Wih1b, Hsz, 6, jt, lds, 30720);
  load_slice(Whh1b, Hsz, 6, jt, lds, 55296);
  __syncthreads();

  const int col  = jt * 16 + lm;
  const int aRow = bt * 32 + r16 * 16 + lm;
  const int rowb = bt * 32 + r16 * 16 + lq * 4;
  const int ldsoff = lq * 128 + lm * 8;

  const float* bi = layer ? bi1 : bi0;
  const float* bh = layer ? bh1 : bh0;
  const float brb  = bi[col] + bh[col];
  const float bzb  = bi[512 + col] + bh[512 + col];
  const float binb = bi[1024 + col];
  const float bhnb = bh[1024 + col];

  unsigned short* h0s[2] = {h0s0, h0s1};
  unsigned short* h1s[2] = {h1s0, h1s1};
  const f32x4 zero = {0.f, 0.f, 0.f, 0.f};
  float hreg0 = 0.f, hreg1 = 0.f, hreg2 = 0.f, hreg3 = 0.f;  // fp32 h carry

  // phase p: layer0 computes h0[p] (p<T); layer1 computes h1[p-1] (p>=1)
  for (int p = 0; p <= Tsz; ++p) {
    const bool active = layer ? (p >= 1) : (p < Tsz);
    if (active) {
      f32x4 ar = zero, az = zero, ain = zero, ahn = zero;
      if (!layer) {
        const unsigned short* Ax = Xt + ((size_t)p * Bsz + aRow) * Isz + lq * 8;
        const unsigned short* Ah = h0s[(p + 1) & 1] + (size_t)aRow * Hsz + lq * 8;
        gemm3<4, 2048, false>(Ax, lds, ldsoff, ar, az, ain);
        gemm3<16, 8192, true>(Ah, lds, ldsoff + 6144, ar, az, ahn);
      } else {
        const unsigned short* Ai = h0s[(p + 1) & 1] + (size_t)aRow * Hsz + lq * 8;
        const unsigned short* Ah = h1s[p & 1]       + (size_t)aRow * Hsz + lq * 8;
        gemm3<16, 8192, true>(Ai, lds, ldsoff + 30720, ar, az, ain);
        gemm3<16, 8192, true>(Ah, lds, ldsoff + 55296, ar, az, ahn);
      }
      unsigned short* hw = layer ? h1s[(p + 1) & 1] : h0s[p & 1];
      float hn0, hn1, hn2, hn3;
      #pragma unroll
      for (int q = 0; q < 4; ++q) {
        const float hp = (q == 0) ? hreg0 : (q == 1) ? hreg1 : (q == 2) ? hreg2 : hreg3;
        const float r = sig_(ar[q] + brb);
        const float z = sig_(az[q] + bzb);
        const float n = tanhf(ain[q] + binb + r * (ahn[q] + bhnb));
        const float hv = (1.f - z) * n + z * hp;
        if (q == 0) hn0 = hv; else if (q == 1) hn1 = hv; else if (q == 2) hn2 = hv; else hn3 = hv;
        stc2(&hw[(size_t)(rowb + q) * Hsz + col], f2bf(hv));
      }
      hreg0 = hn0; hreg1 = hn1; hreg2 = hn2; hreg3 = hn3;
      if (layer && p == Tsz) {
        h1f[(size_t)(rowb + 0) * Hsz + col] = hreg0;
        h1f[(size_t)(rowb + 1) * Hsz + col] = hreg1;
        h1f[(size_t)(rowb + 2) * Hsz + col] = hreg2;
        h1f[(size_t)(rowb + 3) * Hsz + col] = hreg3;
      }
    }
    groupbar(flags, wg, bt, (unsigned)(p + 1));
  }
}

// ---------------- host ----------------
extern "C" void kernel_launch(void* const* d_in, const int* in_sizes, int n_in,
                              void* d_out, int out_size, void* d_ws, size_t ws_size,
                              hipStream_t stream) {
  (void)in_sizes; (void)n_in; (void)out_size; (void)ws_size;
  const float* X    = (const float*)d_in[0];
  const float* Wih0 = (const float*)d_in[1];
  const float* Whh0 = (const float*)d_in[2];
  const float* bi0  = (const float*)d_in[3];
  const float* bh0  = (const float*)d_in[4];
  const float* Wih1 = (const float*)d_in[5];
  const float* Whh1 = (const float*)d_in[6];
  const float* bi1  = (const float*)d_in[7];
  const float* bh1  = (const float*)d_in[8];
  const float* fcw  = (const float*)d_in[9];
  const float* fcb  = (const float*)d_in[10];
  float* out = (float*)d_out;
  char*  ws  = (char*)d_ws;

  size_t off = 0;
  auto alloc = [&](size_t bytes) { size_t r = off; off += (bytes + 255) & ~(size_t)255; return r; };
  unsigned short* Wih0b = (unsigned short*)(ws + alloc((size_t)3 * Hsz * Isz * 2));
  unsigned short* Whh0b = (unsigned short*)(ws + alloc((size_t)3 * Hsz * Hsz * 2));
  unsigned short* Wih1b = (unsigned short*)(ws + alloc((size_t)3 * Hsz * Hsz * 2));
  unsigned short* Whh1b = (unsigned short*)(ws + alloc((size_t)3 * Hsz * Hsz * 2));
  unsigned short* Xt    = (unsigned short*)(ws + alloc((size_t)Bsz * Tsz * Isz * 2));
  const size_t zoff = off;
  float* h1f = (float*)(ws + alloc((size_t)Bsz * Hsz * 4));
  unsigned short* h0s0 = (unsigned short*)(ws + alloc((size_t)Bsz * Hsz * 2));
  unsigned short* h0s1 = (unsigned short*)(ws + alloc((size_t)Bsz * Hsz * 2));
  unsigned short* h1s0 = (unsigned short*)(ws + alloc((size_t)Bsz * Hsz * 2));
  unsigned short* h1s1 = (unsigned short*)(ws + alloc((size_t)Bsz * Hsz * 2));
  unsigned* flags = (unsigned*)(ws + alloc(NWG * 32 * 4));   // 128B per WG
  const size_t zbytes = off - zoff;

  auto cast = [&](const float* s, unsigned short* d, int n) {
    int n4 = n / 4;
    cast_bf16_k<<<(n4 + 255) / 256, 256, 0, stream>>>(s, d, n4);
  };
  cast(Wih0, Wih0b, 3 * Hsz * Isz);
  cast(Whh0, Whh0b, 3 * Hsz * Hsz);
  cast(Wih1, Wih1b, 3 * Hsz * Hsz);
  cast(Whh1, Whh1b, 3 * Hsz * Hsz);
  castX_k<<<(Bsz * Tsz * Isz / 4 + 255) / 256, 256, 0, stream>>>(X, Xt);
  hipMemsetAsync(ws + zoff, 0, zbytes, stream);   // h states + flags = 0

  (void)hipFuncSetAttribute((const void*)gru_persist,
                            hipFuncAttributeMaxDynamicSharedMemorySize, 159744);
  gru_persist<<<NWG, 256, 159744, stream>>>(Xt, Wih0b, Whh0b, Wih1b, Whh1b,
                                            bi0, bh0, bi1, bh1,
                                            h1f, h0s0, h0s1, h1s0, h1s1, flags);
  fc_k<<<1, 256, 0, stream>>>(h1f, fcw, fcb, out);
}